// Round 1
// baseline (313.219 us; speedup 1.0000x reference)
//
#include <hip/hip_runtime.h>

// ---------------------------------------------------------------------------
// NATTEN cross attention, MI355X round 1 (correctness-first).
// Shapes: q (1,256,96,96) k (1,256,48,48) v (1,128,48,48)
// kernel_size=7 dilation=2 N_HEADS=8 d_head=32, output (1,128,96,96) f32.
// Key identity: nearest-exact 2x upsample + dilation-2 NATTEN window cancel:
//   key/value grid pos for query (x,y), tap (th,tw) =
//   (clip(x/2-3,0,41)+th, clip(y/2-3,0,41)+tw) in the native 48x48 grid.
// ---------------------------------------------------------------------------

#define C_IN   256
#define C_V    128
#define HQ     96
#define WQ     96
#define HK     48
#define WK     48
#define NPOS_Q (HQ*WQ)    // 9216
#define NPOS_K (HK*WK)    // 2304
#define NH     8
#define DH     32
#define KS     7
#define K2     49
#define KP     264        // LDS pitch (floats) for staged K rows

// ---- projection: out_t[pos][o] = b[o] + sum_c w[o][c] * x[c][pos] ----------
// grid: (npos/256, C_IN/32), block 256. thread = pos, 32-wide o tile.
__global__ __launch_bounds__(256) void proj_kernel(
    const float* __restrict__ x, const float* __restrict__ w,
    const float* __restrict__ b, float* __restrict__ out_t, int npos) {
  const int pos = blockIdx.x * 256 + threadIdx.x;
  const int ob  = blockIdx.y * 32;
  float acc[32];
#pragma unroll
  for (int i = 0; i < 32; ++i) acc[i] = 0.f;

  for (int c0 = 0; c0 < C_IN; c0 += 8) {
    float xv[8];
#pragma unroll
    for (int j = 0; j < 8; ++j) xv[j] = x[(c0 + j) * npos + pos];
#pragma unroll
    for (int oo = 0; oo < 32; ++oo) {
#pragma unroll
      for (int j = 0; j < 8; ++j)
        acc[oo] += w[(ob + oo) * C_IN + c0 + j] * xv[j];   // w: wave-uniform -> s_load
    }
  }
#pragma unroll
  for (int oo = 0; oo < 32; oo += 4) {
    float4 vv;
    vv.x = acc[oo + 0] + b[ob + oo + 0];
    vv.y = acc[oo + 1] + b[ob + oo + 1];
    vv.z = acc[oo + 2] + b[ob + oo + 2];
    vv.w = acc[oo + 3] + b[ob + oo + 3];
    *(float4*)&out_t[pos * C_IN + ob + oo] = vv;
  }
}

// ---- v transpose: vt[pos][c] = v[c][pos] ----------------------------------
// grid 36 (64 pos per block), block 256, LDS tile, conflict-free.
__global__ __launch_bounds__(256) void transpose_v(
    const float* __restrict__ v, float* __restrict__ vt) {
  __shared__ float tile[C_V * 65];
  const int p0 = blockIdx.x * 64;
  const int u  = threadIdx.x;
  for (int i = u; i < C_V * 64; i += 256) {
    int c = i >> 6, p = i & 63;
    tile[c * 65 + p] = v[c * NPOS_K + p0 + p];
  }
  __syncthreads();
  for (int i = u; i < C_V * 64; i += 256) {
    int p = i >> 7, c = i & 127;
    vt[(p0 + p) * C_V + c] = tile[c * 65 + p];
  }
}

// ---- fused neighborhood attention -----------------------------------------
// block = 256 threads, handles the 2x2 query tile (2a..2a+1, 2b..2b+1);
// all 4 queries share one 7x7 window at (sh..sh+6, sw..sw+6) in the 48-grid.
__global__ __launch_bounds__(256) void natten_attn(
    const float* __restrict__ qt, const float* __restrict__ kt,
    const float* __restrict__ vt, float* __restrict__ out) {
  __shared__ float q_s[4 * C_IN];          //  4 KB
  __shared__ float kv_s[K2 * KP];          // 50.5 KB (k window, later reused for v)
  __shared__ float l_s[32 * K2];           //  6.1 KB  (qi*8+h rows)
  __shared__ float pm_s[4 * K2];
  __shared__ float rinv_s[32];

  const int u  = threadIdx.x;
  const int a  = blockIdx.x;               // 0..47
  const int b  = blockIdx.y;               // 0..47
  const int sh = min(max(a - 3, 0), HK - KS);
  const int sw = min(max(b - 3, 0), WK - KS);

  // stage q rows (4 queries x 256 ch), coalesced
  for (int i = u; i < 4 * C_IN; i += 256) {
    int qi = i >> 8, c = i & 255;
    int qx = 2 * a + (qi >> 1), qy = 2 * b + (qi & 1);
    q_s[i] = qt[(qx * WQ + qy) * C_IN + c];
  }
  // stage k window (49 rows x 256 ch), coalesced
  for (int i = u; i < K2 * C_IN; i += 256) {
    int t = i >> 8, c = i & 255;
    int th = t / KS, tw = t - th * KS;
    kv_s[t * KP + c] = kt[((sh + th) * WK + (sw + tw)) * C_IN + c];
  }
  __syncthreads();

  // logits: 4 queries x 8 heads x 49 taps, dot over 32 dims (float4 LDS reads)
  const float scale = 0.17677669529663687f;  // 32^-0.5
  for (int D = u; D < 4 * NH * K2; D += 256) {
    int qi = D / (NH * K2);
    int r  = D - qi * (NH * K2);
    int h  = r / K2;
    int t  = r - h * K2;
    const float4* q4 = (const float4*)&q_s[qi * C_IN + h * DH];
    const float4* k4 = (const float4*)&kv_s[t * KP + h * DH];
    float s = 0.f;
#pragma unroll
    for (int j = 0; j < 8; ++j) {
      float4 qv = q4[j], kv = k4[j];
      s += qv.x * kv.x + qv.y * kv.y + qv.z * kv.z + qv.w * kv.w;
    }
    l_s[(qi * NH + h) * K2 + t] = s * scale;
  }
  __syncthreads();

  // v window loads (overwrites k region; overlapped with softmax below)
  for (int i = u; i < K2 * C_V; i += 256) {
    int t = i >> 7, c = i & 127;
    int th = t / KS, tw = t - th * KS;
    kv_s[i] = vt[((sh + th) * WK + (sw + tw)) * C_V + c];
  }

  // softmax over t per (qi,h) row: 32 rows x 8 lanes each
  {
    const int row = u >> 3, j = u & 7;
    float mx = -1e30f;
    for (int t = j; t < K2; t += 8) mx = fmaxf(mx, l_s[row * K2 + t]);
    mx = fmaxf(mx, __shfl_xor(mx, 1));
    mx = fmaxf(mx, __shfl_xor(mx, 2));
    mx = fmaxf(mx, __shfl_xor(mx, 4));
    float sm = 0.f;
    for (int t = j; t < K2; t += 8) {
      float e = __expf(l_s[row * K2 + t] - mx);
      l_s[row * K2 + t] = e;
      sm += e;
    }
    sm += __shfl_xor(sm, 1);
    sm += __shfl_xor(sm, 2);
    sm += __shfl_xor(sm, 4);
    if (j == 0) rinv_s[row] = 1.f / (8.f * sm);
  }
  __syncthreads();

  // head-mean of normalized probs: pm[qi][t] = sum_h p[qi][h][t] / (8*rowsum)
  for (int i = u; i < 4 * K2; i += 256) {
    int qi = i / K2, t = i - qi * K2;
    float s2 = 0.f;
#pragma unroll
    for (int h = 0; h < NH; ++h) s2 += l_s[(qi * NH + h) * K2 + t] * rinv_s[qi * NH + h];
    pm_s[i] = s2;
  }
  __syncthreads();

  // PV: out[c,x,y] = sum_t pm[t] * v_s[t][c]; lanes walk c -> conflict-free
  for (int i = u; i < 4 * C_V; i += 256) {
    int qi = i >> 7, c = i & 127;
    float acc = 0.f;
    for (int t = 0; t < K2; ++t) acc += pm_s[qi * K2 + t] * kv_s[t * C_V + c];
    int qx = 2 * a + (qi >> 1), qy = 2 * b + (qi & 1);
    out[c * NPOS_Q + qx * WQ + qy] = acc;
  }
}

// ---------------------------------------------------------------------------
extern "C" void kernel_launch(void* const* d_in, const int* in_sizes, int n_in,
                              void* d_out, int out_size, void* d_ws, size_t ws_size,
                              hipStream_t stream) {
  const float* q   = (const float*)d_in[0];
  const float* k   = (const float*)d_in[1];
  const float* v   = (const float*)d_in[2];
  const float* w_q = (const float*)d_in[3];
  const float* b_q = (const float*)d_in[4];
  const float* w_k = (const float*)d_in[5];
  const float* b_k = (const float*)d_in[6];
  float* out = (float*)d_out;

  float* qt = (float*)d_ws;                  // [9216][256]
  float* kt = qt + (size_t)NPOS_Q * C_IN;    // [2304][256]
  float* vt = kt + (size_t)NPOS_K * C_IN;    // [2304][128]

  proj_kernel<<<dim3(NPOS_Q / 256, C_IN / 32), 256, 0, stream>>>(q, w_q, b_q, qt, NPOS_Q);
  proj_kernel<<<dim3(NPOS_K / 256, C_IN / 32), 256, 0, stream>>>(k, w_k, b_k, kt, NPOS_K);
  transpose_v<<<NPOS_K / 64, 256, 0, stream>>>(v, vt);
  natten_attn<<<dim3(HQ / 2, WQ / 2), 256, 0, stream>>>(qt, kt, vt, out);
}

// Round 2
// 96.827 us; speedup vs baseline: 3.2349x; 3.2349x over previous
//
#include <hip/hip_runtime.h>

// ---------------------------------------------------------------------------
// NATTEN cross attention, MI355X round 2: tiled-GEMM projections.
// Shapes: q (1,256,96,96) k (1,256,48,48) v (1,128,48,48)
// kernel_size=7 dilation=2 N_HEADS=8 d_head=32, output (1,128,96,96) f32.
// Window identity: nearest-exact 2x upsample + dilation-2 NATTEN cancel:
//   key/value tap for query (x,y) = (clip(x/2-3,0,41)+th, clip(y/2-3,0,41)+tw).
// ---------------------------------------------------------------------------

#define C_IN   256
#define C_V    128
#define HQ     96
#define WQ     96
#define HK     48
#define WK     48
#define NPOS_Q (HQ*WQ)    // 9216
#define NPOS_K (HK*WK)    // 2304
#define NH     8
#define DH     32
#define KS     7
#define K2     49
#define KP     264        // LDS pitch (floats) for staged K rows in attention

#define TQ  (NPOS_Q/64)   // 144 M-tiles for Q proj
#define TK  (NPOS_K/64)   // 36  M-tiles for K proj

// ---- fused dual projection GEMM -------------------------------------------
// out_t[pos][o] = b[o] + sum_c w[o][c] * x[c][pos]
// One dispatch covers both GEMMs: blockIdx.x < TQ -> Q tiles, else K tiles.
// Tile: 64 pos x 64 o, KC=16, 256 threads, 4x4 acc/thread.
__global__ __launch_bounds__(256) void proj_gemm(
    const float* __restrict__ xq, const float* __restrict__ xk,
    const float* __restrict__ wq, const float* __restrict__ wk,
    const float* __restrict__ bq, const float* __restrict__ bk,
    float* __restrict__ qt, float* __restrict__ kt) {
  __shared__ float xs[16][68];
  __shared__ float ws[16][68];

  const int mb = blockIdx.x;
  const float* x; const float* w; const float* bias; float* outp;
  int npos, m0;
  if (mb < TQ) { x = xq; w = wq; bias = bq; outp = qt; npos = NPOS_Q; m0 = mb * 64; }
  else         { x = xk; w = wk; bias = bk; outp = kt; npos = NPOS_K; m0 = (mb - TQ) * 64; }
  const int n0 = blockIdx.y * 64;

  const int t  = threadIdx.x;
  const int tm = t & 15;          // pos-frag 0..15
  const int tn = t >> 4;          // o-frag  0..15

  // load indices
  const int lx_kk = t >> 4;            // 0..15  (x: row kk, 16 float4/row)
  const int lx_m4 = (t & 15) * 4;      // float4 col
  const int lw_o  = t >> 2;            // 0..63  (w: row o, 4 float4/row)
  const int lw_c4 = (t & 3) * 4;       // c quad within chunk

  float acc[4][4];
#pragma unroll
  for (int i = 0; i < 4; ++i)
#pragma unroll
    for (int j = 0; j < 4; ++j) acc[i][j] = 0.f;

  for (int c0 = 0; c0 < C_IN; c0 += 16) {
    float4 xv = *(const float4*)&x[(size_t)(c0 + lx_kk) * npos + m0 + lx_m4];
    float4 wv = *(const float4*)&w[(size_t)(n0 + lw_o) * C_IN + c0 + lw_c4];
    __syncthreads();   // protect LDS from previous iteration's readers
    *(float4*)&xs[lx_kk][lx_m4] = xv;
    ws[lw_c4 + 0][lw_o] = wv.x;
    ws[lw_c4 + 1][lw_o] = wv.y;
    ws[lw_c4 + 2][lw_o] = wv.z;
    ws[lw_c4 + 3][lw_o] = wv.w;
    __syncthreads();

#pragma unroll
    for (int kk = 0; kk < 16; ++kk) {
      float4 a4 = *(const float4*)&xs[kk][tm * 4];
      float4 b4 = *(const float4*)&ws[kk][tn * 4];
      const float av[4] = {a4.x, a4.y, a4.z, a4.w};
      const float bv[4] = {b4.x, b4.y, b4.z, b4.w};
#pragma unroll
      for (int i = 0; i < 4; ++i)
#pragma unroll
        for (int j = 0; j < 4; ++j) acc[i][j] += av[i] * bv[j];
    }
  }

  const float4 bias4 = *(const float4*)&bias[n0 + tn * 4];
#pragma unroll
  for (int i = 0; i < 4; ++i) {
    float4 vv;
    vv.x = acc[i][0] + bias4.x;
    vv.y = acc[i][1] + bias4.y;
    vv.z = acc[i][2] + bias4.z;
    vv.w = acc[i][3] + bias4.w;
    *(float4*)&outp[(size_t)(m0 + tm * 4 + i) * C_IN + n0 + tn * 4] = vv;
  }
}

// ---- v transpose: vt[pos][c] = v[c][pos] ----------------------------------
__global__ __launch_bounds__(256) void transpose_v(
    const float* __restrict__ v, float* __restrict__ vt) {
  __shared__ float tile[C_V * 65];
  const int p0 = blockIdx.x * 64;
  const int u  = threadIdx.x;
  for (int i = u; i < C_V * 64; i += 256) {
    int c = i >> 6, p = i & 63;
    tile[c * 65 + p] = v[c * NPOS_K + p0 + p];
  }
  __syncthreads();
  for (int i = u; i < C_V * 64; i += 256) {
    int p = i >> 7, c = i & 127;
    vt[(p0 + p) * C_V + c] = tile[c * 65 + p];
  }
}

// ---- fused neighborhood attention -----------------------------------------
// block = 256 threads, handles the 2x2 query tile (2a..2a+1, 2b..2b+1);
// all 4 queries share one 7x7 window at (sh..sh+6, sw..sw+6) in the 48-grid.
__global__ __launch_bounds__(256) void natten_attn(
    const float* __restrict__ qt, const float* __restrict__ kt,
    const float* __restrict__ vt, float* __restrict__ out) {
  __shared__ float q_s[4 * C_IN];          //  4 KB
  __shared__ float kv_s[K2 * KP];          // 50.5 KB (k window, later reused for v)
  __shared__ float l_s[32 * K2];           //  6.1 KB  (qi*8+h rows)
  __shared__ float pm_s[4 * K2];
  __shared__ float rinv_s[32];

  const int u  = threadIdx.x;
  const int a  = blockIdx.x;               // 0..47
  const int b  = blockIdx.y;               // 0..47
  const int sh = min(max(a - 3, 0), HK - KS);
  const int sw = min(max(b - 3, 0), WK - KS);

  // stage q rows (4 queries x 256 ch), coalesced
  for (int i = u; i < 4 * C_IN; i += 256) {
    int qi = i >> 8, c = i & 255;
    int qx = 2 * a + (qi >> 1), qy = 2 * b + (qi & 1);
    q_s[i] = qt[(qx * WQ + qy) * C_IN + c];
  }
  // stage k window (49 rows x 256 ch), coalesced
  for (int i = u; i < K2 * C_IN; i += 256) {
    int t = i >> 8, c = i & 255;
    int th = t / KS, tw = t - th * KS;
    kv_s[t * KP + c] = kt[((sh + th) * WK + (sw + tw)) * C_IN + c];
  }
  __syncthreads();

  // logits: 4 queries x 8 heads x 49 taps, dot over 32 dims (float4 LDS reads)
  const float scale = 0.17677669529663687f;  // 32^-0.5
  for (int D = u; D < 4 * NH * K2; D += 256) {
    int qi = D / (NH * K2);
    int r  = D - qi * (NH * K2);
    int h  = r / K2;
    int t  = r - h * K2;
    const float4* q4 = (const float4*)&q_s[qi * C_IN + h * DH];
    const float4* k4 = (const float4*)&kv_s[t * KP + h * DH];
    float s = 0.f;
#pragma unroll
    for (int j = 0; j < 8; ++j) {
      float4 qv = q4[j], kv = k4[j];
      s += qv.x * kv.x + qv.y * kv.y + qv.z * kv.z + qv.w * kv.w;
    }
    l_s[(qi * NH + h) * K2 + t] = s * scale;
  }
  __syncthreads();

  // v window loads (overwrites k region; overlapped with softmax below)
  for (int i = u; i < K2 * C_V; i += 256) {
    int t = i >> 7, c = i & 127;
    int th = t / KS, tw = t - th * KS;
    kv_s[i] = vt[((sh + th) * WK + (sw + tw)) * C_V + c];
  }

  // softmax over t per (qi,h) row: 32 rows x 8 lanes each
  {
    const int row = u >> 3, j = u & 7;
    float mx = -1e30f;
    for (int t = j; t < K2; t += 8) mx = fmaxf(mx, l_s[row * K2 + t]);
    mx = fmaxf(mx, __shfl_xor(mx, 1));
    mx = fmaxf(mx, __shfl_xor(mx, 2));
    mx = fmaxf(mx, __shfl_xor(mx, 4));
    float sm = 0.f;
    for (int t = j; t < K2; t += 8) {
      float e = __expf(l_s[row * K2 + t] - mx);
      l_s[row * K2 + t] = e;
      sm += e;
    }
    sm += __shfl_xor(sm, 1);
    sm += __shfl_xor(sm, 2);
    sm += __shfl_xor(sm, 4);
    if (j == 0) rinv_s[row] = 1.f / (8.f * sm);
  }
  __syncthreads();

  // head-mean of normalized probs: pm[qi][t] = sum_h p[qi][h][t] / (8*rowsum)
  for (int i = u; i < 4 * K2; i += 256) {
    int qi = i / K2, t = i - qi * K2;
    float s2 = 0.f;
#pragma unroll
    for (int h = 0; h < NH; ++h) s2 += l_s[(qi * NH + h) * K2 + t] * rinv_s[qi * NH + h];
    pm_s[i] = s2;
  }
  __syncthreads();

  // PV: out[c,x,y] = sum_t pm[t] * v_s[t][c]; lanes walk c -> conflict-free
  for (int i = u; i < 4 * C_V; i += 256) {
    int qi = i >> 7, c = i & 127;
    float acc = 0.f;
    for (int t = 0; t < K2; ++t) acc += pm_s[qi * K2 + t] * kv_s[t * C_V + c];
    int qx = 2 * a + (qi >> 1), qy = 2 * b + (qi & 1);
    out[c * NPOS_Q + qx * WQ + qy] = acc;
  }
}

// ---------------------------------------------------------------------------
extern "C" void kernel_launch(void* const* d_in, const int* in_sizes, int n_in,
                              void* d_out, int out_size, void* d_ws, size_t ws_size,
                              hipStream_t stream) {
  const float* q   = (const float*)d_in[0];
  const float* k   = (const float*)d_in[1];
  const float* v   = (const float*)d_in[2];
  const float* w_q = (const float*)d_in[3];
  const float* b_q = (const float*)d_in[4];
  const float* w_k = (const float*)d_in[5];
  const float* b_k = (const float*)d_in[6];
  float* out = (float*)d_out;

  float* qt = (float*)d_ws;                  // [9216][256]
  float* kt = qt + (size_t)NPOS_Q * C_IN;    // [2304][256]
  float* vt = kt + (size_t)NPOS_K * C_IN;    // [2304][128]

  proj_gemm<<<dim3(TQ + TK, 4), 256, 0, stream>>>(q, k, w_q, w_k, b_q, b_k, qt, kt);
  transpose_v<<<NPOS_K / 64, 256, 0, stream>>>(v, vt);
  natten_attn<<<dim3(HQ / 2, WQ / 2), 256, 0, stream>>>(qt, kt, vt, out);
}

// Round 3
// 90.408 us; speedup vs baseline: 3.4645x; 1.0710x over previous
//
#include <hip/hip_runtime.h>

// ---------------------------------------------------------------------------
// NATTEN cross attention, MI355X round 3.
// Shapes: q (1,256,96,96) k (1,256,48,48) v (1,128,48,48)
// kernel_size=7 dilation=2 N_HEADS=8 d_head=32, output (1,128,96,96) f32.
// Window identity: nearest-exact 2x upsample + dilation-2 NATTEN cancel:
//   key/value tap for query (x,y) = (clip(x/2-3,0,41)+th, clip(y/2-3,0,41)+tw).
// Round-3 changes:
//   * attn: k LDS pitch 264 -> 260 floats (65 quads, ODD) so b128 granule
//     index = (t + j) mod 8 covers all 8 LDS 16B-granules -> kills the 3M
//     bank conflicts in the logits phase. Staging now writes float4 quads.
//   * proj: double-buffered LDS -> 1 barrier per K-chunk instead of 2.
// ---------------------------------------------------------------------------

#define C_IN   256
#define C_V    128
#define HQ     96
#define WQ     96
#define HK     48
#define WK     48
#define NPOS_Q (HQ*WQ)    // 9216
#define NPOS_K (HK*WK)    // 2304
#define NH     8
#define DH     32
#define KS     7
#define K2     49
#define KQ     65         // k LDS pitch in QUADS (odd -> conflict-free b128)
#define KP     (KQ*4)     // 260 floats

#define TQ  (NPOS_Q/64)   // 144 M-tiles for Q proj
#define TK  (NPOS_K/64)   // 36  M-tiles for K proj

// ---- fused dual projection GEMM -------------------------------------------
// out_t[pos][o] = b[o] + sum_c w[o][c] * x[c][pos]
// blockIdx.x < TQ -> Q tiles, else K tiles. 64x64 tile, KC=16, 4x4 acc.
// Double-buffered LDS: single __syncthreads per chunk.
__global__ __launch_bounds__(256) void proj_gemm(
    const float* __restrict__ xq, const float* __restrict__ xk,
    const float* __restrict__ wq, const float* __restrict__ wk,
    const float* __restrict__ bq, const float* __restrict__ bk,
    float* __restrict__ qt, float* __restrict__ kt) {
  __shared__ float xs[2][16][68];
  __shared__ float ws[2][16][68];

  const int mb = blockIdx.x;
  const float* x; const float* w; const float* bias; float* outp;
  int npos, m0;
  if (mb < TQ) { x = xq; w = wq; bias = bq; outp = qt; npos = NPOS_Q; m0 = mb * 64; }
  else         { x = xk; w = wk; bias = bk; outp = kt; npos = NPOS_K; m0 = (mb - TQ) * 64; }
  const int n0 = blockIdx.y * 64;

  const int t  = threadIdx.x;
  const int tm = t & 15;          // pos-frag 0..15
  const int tn = t >> 4;          // o-frag  0..15

  const int lx_kk = t >> 4;            // x: row kk, 16 float4/row
  const int lx_m4 = (t & 15) * 4;
  const int lw_o  = t >> 2;            // w: row o, 4 float4/row
  const int lw_c4 = (t & 3) * 4;

  float acc[4][4];
#pragma unroll
  for (int i = 0; i < 4; ++i)
#pragma unroll
    for (int j = 0; j < 4; ++j) acc[i][j] = 0.f;

  float4 xv = *(const float4*)&x[(size_t)lx_kk * npos + m0 + lx_m4];
  float4 wv = *(const float4*)&w[(size_t)(n0 + lw_o) * C_IN + lw_c4];

  int p = 0;
  for (int c0 = 0; c0 < C_IN; c0 += 16, p ^= 1) {
    *(float4*)&xs[p][lx_kk][lx_m4] = xv;
    ws[p][lw_c4 + 0][lw_o] = wv.x;
    ws[p][lw_c4 + 1][lw_o] = wv.y;
    ws[p][lw_c4 + 2][lw_o] = wv.z;
    ws[p][lw_c4 + 3][lw_o] = wv.w;
    if (c0 + 16 < C_IN) {
      xv = *(const float4*)&x[(size_t)(c0 + 16 + lx_kk) * npos + m0 + lx_m4];
      wv = *(const float4*)&w[(size_t)(n0 + lw_o) * C_IN + c0 + 16 + lw_c4];
    }
    __syncthreads();
#pragma unroll
    for (int kk = 0; kk < 16; ++kk) {
      float4 a4 = *(const float4*)&xs[p][kk][tm * 4];
      float4 b4 = *(const float4*)&ws[p][kk][tn * 4];
      const float av[4] = {a4.x, a4.y, a4.z, a4.w};
      const float bv[4] = {b4.x, b4.y, b4.z, b4.w};
#pragma unroll
      for (int i = 0; i < 4; ++i)
#pragma unroll
        for (int j = 0; j < 4; ++j) acc[i][j] += av[i] * bv[j];
    }
  }

  const float4 bias4 = *(const float4*)&bias[n0 + tn * 4];
#pragma unroll
  for (int i = 0; i < 4; ++i) {
    float4 vv;
    vv.x = acc[i][0] + bias4.x;
    vv.y = acc[i][1] + bias4.y;
    vv.z = acc[i][2] + bias4.z;
    vv.w = acc[i][3] + bias4.w;
    *(float4*)&outp[(size_t)(m0 + tm * 4 + i) * C_IN + n0 + tn * 4] = vv;
  }
}

// ---- v transpose: vt[pos][c] = v[c][pos] ----------------------------------
__global__ __launch_bounds__(256) void transpose_v(
    const float* __restrict__ v, float* __restrict__ vt) {
  __shared__ float tile[C_V * 65];
  const int p0 = blockIdx.x * 64;
  const int u  = threadIdx.x;
  for (int i = u; i < C_V * 64; i += 256) {
    int c = i >> 6, p = i & 63;
    tile[c * 65 + p] = v[c * NPOS_K + p0 + p];
  }
  __syncthreads();
  for (int i = u; i < C_V * 64; i += 256) {
    int p = i >> 7, c = i & 127;
    vt[(p0 + p) * C_V + c] = tile[c * 65 + p];
  }
}

// ---- fused neighborhood attention -----------------------------------------
// block = 256 threads, handles the 2x2 query tile (2a..2a+1, 2b..2b+1);
// all 4 queries share one 7x7 window at (sh..sh+6, sw..sw+6) in the 48-grid.
__global__ __launch_bounds__(256) void natten_attn(
    const float* __restrict__ qt, const float* __restrict__ kt,
    const float* __restrict__ vt, float* __restrict__ out) {
  __shared__ float q_s[4 * C_IN];          //  4 KB
  __shared__ float kv_s[K2 * KP];          // 51 KB (k window, later reused for v)
  __shared__ float l_s[32 * K2];           //  6.1 KB  (qi*8+h rows)
  __shared__ float pm_s[4 * K2];
  __shared__ float rinv_s[32];

  const int u  = threadIdx.x;
  const int a  = blockIdx.x;               // 0..47
  const int b  = blockIdx.y;               // 0..47
  const int sh = min(max(a - 3, 0), HK - KS);
  const int sw = min(max(b - 3, 0), WK - KS);

  // stage q rows (4 queries x 256 ch), coalesced
  for (int i = u; i < 4 * C_IN; i += 256) {
    int qi = i >> 8, c = i & 255;
    int qx = 2 * a + (qi >> 1), qy = 2 * b + (qi & 1);
    q_s[i] = qt[(qx * WQ + qy) * C_IN + c];
  }
  // stage k window (49 rows x 64 quads), quad-granular, odd pitch -> all 8
  // LDS granules covered by both the writes here and the b128 reads below.
  {
    float4* kv4 = (float4*)kv_s;
    for (int i = u; i < K2 * 64; i += 256) {
      int tp = i >> 6, j = i & 63;
      int th = tp / KS, tw = tp - th * KS;
      kv4[tp * KQ + j] =
          *(const float4*)&kt[((sh + th) * WK + (sw + tw)) * C_IN + 4 * j];
    }
  }
  __syncthreads();

  // logits: 4 queries x 8 heads x 49 taps, dot over 32 dims (float4 LDS reads)
  const float scale = 0.17677669529663687f;  // 32^-0.5
  for (int D = u; D < 4 * NH * K2; D += 256) {
    int qi = D / (NH * K2);
    int r  = D - qi * (NH * K2);
    int h  = r / K2;
    int t  = r - h * K2;
    const float4* q4 = (const float4*)&q_s[qi * C_IN + h * DH];
    const float4* k4 = (const float4*)&kv_s[t * KP + h * DH];
    float s = 0.f;
#pragma unroll
    for (int j = 0; j < 8; ++j) {
      float4 qv = q4[j], kv = k4[j];
      s += qv.x * kv.x + qv.y * kv.y + qv.z * kv.z + qv.w * kv.w;
    }
    l_s[(qi * NH + h) * K2 + t] = s * scale;
  }
  __syncthreads();

  // v window loads (overwrites k region; overlapped with softmax below)
  for (int i = u; i < K2 * C_V; i += 256) {
    int t = i >> 7, c = i & 127;
    int th = t / KS, tw = t - th * KS;
    kv_s[i] = vt[((sh + th) * WK + (sw + tw)) * C_V + c];
  }

  // softmax over t per (qi,h) row: 32 rows x 8 lanes each
  {
    const int row = u >> 3, j = u & 7;
    float mx = -1e30f;
    for (int t = j; t < K2; t += 8) mx = fmaxf(mx, l_s[row * K2 + t]);
    mx = fmaxf(mx, __shfl_xor(mx, 1));
    mx = fmaxf(mx, __shfl_xor(mx, 2));
    mx = fmaxf(mx, __shfl_xor(mx, 4));
    float sm = 0.f;
    for (int t = j; t < K2; t += 8) {
      float e = __expf(l_s[row * K2 + t] - mx);
      l_s[row * K2 + t] = e;
      sm += e;
    }
    sm += __shfl_xor(sm, 1);
    sm += __shfl_xor(sm, 2);
    sm += __shfl_xor(sm, 4);
    if (j == 0) rinv_s[row] = 1.f / (8.f * sm);
  }
  __syncthreads();

  // head-mean of normalized probs: pm[qi][t] = sum_h p[qi][h][t] / (8*rowsum)
  for (int i = u; i < 4 * K2; i += 256) {
    int qi = i / K2, t = i - qi * K2;
    float s2 = 0.f;
#pragma unroll
    for (int h = 0; h < NH; ++h) s2 += l_s[(qi * NH + h) * K2 + t] * rinv_s[qi * NH + h];
    pm_s[i] = s2;
  }
  __syncthreads();

  // PV: out[c,x,y] = sum_t pm[t] * v_s[t][c]; lanes walk c -> conflict-free
  for (int i = u; i < 4 * C_V; i += 256) {
    int qi = i >> 7, c = i & 127;
    float acc = 0.f;
    for (int t = 0; t < K2; ++t) acc += pm_s[qi * K2 + t] * kv_s[t * C_V + c];
    int qx = 2 * a + (qi >> 1), qy = 2 * b + (qi & 1);
    out[c * NPOS_Q + qx * WQ + qy] = acc;
  }
}

// ---------------------------------------------------------------------------
extern "C" void kernel_launch(void* const* d_in, const int* in_sizes, int n_in,
                              void* d_out, int out_size, void* d_ws, size_t ws_size,
                              hipStream_t stream) {
  const float* q   = (const float*)d_in[0];
  const float* k   = (const float*)d_in[1];
  const float* v   = (const float*)d_in[2];
  const float* w_q = (const float*)d_in[3];
  const float* b_q = (const float*)d_in[4];
  const float* w_k = (const float*)d_in[5];
  const float* b_k = (const float*)d_in[6];
  float* out = (float*)d_out;

  float* qt = (float*)d_ws;                  // [9216][256]
  float* kt = qt + (size_t)NPOS_Q * C_IN;    // [2304][256]
  float* vt = kt + (size_t)NPOS_K * C_IN;    // [2304][128]

  proj_gemm<<<dim3(TQ + TK, 4), 256, 0, stream>>>(q, k, w_q, w_k, b_q, b_k, qt, kt);
  transpose_v<<<NPOS_K / 64, 256, 0, stream>>>(v, vt);
  natten_attn<<<dim3(HQ / 2, WQ / 2), 256, 0, stream>>>(qt, kt, vt, out);
}